// Round 6
// baseline (477.131 us; speedup 1.0000x reference)
//
#include <hip/hip_runtime.h>
#include <hip/hip_bf16.h>
#include <stdint.h>
#include <stddef.h>

typedef __bf16 bf16;
typedef __attribute__((ext_vector_type(4))) __bf16 bf16x4;
typedef __attribute__((ext_vector_type(8))) __bf16 bf16x8;
typedef __attribute__((ext_vector_type(4))) float f32x4;

#define BATCH 4096
#define DIM 1024
#define ODIM 1024
#define K3 3072
#define NB 512          // grid size; 2 blocks/CU forced resident

// workspace layout (bytes)
#define WS_P      0          // bf16 [4096][3072] = 25165824
// pmin/pmax alias the head of P: fully consumed (phase 2) before P written (phase 3)
#define WS_PMIN   0          // f32 [512][1024] = 2 MB
#define WS_PMAX   2097152    // f32 [512][1024] = 2 MB
#define WS_CB     25165824   // bf16 [1024][3072] = 6291456
#define WS_BIAS   31457280   // f32 [1024]
#define WS_MINV   31461376   // f32 [1024]
#define WS_SCALE  31465472   // f32 [1024]
#define WS_SYNC   31469568   // int [4]

#define ASYNC16(g, l)                                                          \
  __builtin_amdgcn_global_load_lds(                                            \
      (__attribute__((address_space(1))) void*)(g),                            \
      (__attribute__((address_space(3))) void*)(l), 16, 0, 0)

// device-scope grid barrier (G16 pattern). Safe: all NB blocks resident
// (grid = 2*256, __launch_bounds__(256,2), 35 KB LDS, <=256 VGPR).
__device__ __forceinline__ void gsync(int* cnt) {
  __syncthreads();  // emits s_waitcnt vmcnt(0): this wave's stores are in L2
  if (threadIdx.x == 0) {
    __threadfence();  // release: write back L2 -> device coherent point
    __hip_atomic_fetch_add(cnt, 1, __ATOMIC_RELEASE, __HIP_MEMORY_SCOPE_AGENT);
    while (__hip_atomic_load(cnt, __ATOMIC_ACQUIRE, __HIP_MEMORY_SCOPE_AGENT) < NB)
      __builtin_amdgcn_s_sleep(8);
    __threadfence();  // acquire: invalidate L1 so phase N+1 sees remote writes
  }
  __syncthreads();
}

// GEMM phase tiling: 128x128 block tile, BK=64, split-K x2 (K half = 1536).
// 4 waves each 64x64 (4x4 frags 16x16x32) — R5-proven zero-conflict pattern.
#define BM 128
#define BN 128
#define BKE 64
#define NIT (1536 / BKE)  // 24

__global__ __launch_bounds__(256, 2) void k_fused(
    const float* __restrict__ x, const float* __restrict__ sp,
    bf16* __restrict__ P, bf16* __restrict__ CB, float* __restrict__ bias,
    float* __restrict__ pmin, float* __restrict__ pmax,
    float* __restrict__ minv, float* __restrict__ scale,
    int* __restrict__ sync, float* __restrict__ out) {
  __shared__ bf16 sA[BM * BKE];      // 16 KB
  __shared__ bf16 sB[BN * BKE];      // 16 KB
  __shared__ float smn[16][17], smx[16][17];
  __shared__ float red[4];

  const int bid = blockIdx.x;
  const int t = threadIdx.x;

  // ---- P1: partial min/max, 8 rows per block ----
  {
    const float* xp = x + (size_t)bid * 8 * DIM + (t << 2);
    f32x4 mn = {1e30f, 1e30f, 1e30f, 1e30f};
    f32x4 mx = {-1e30f, -1e30f, -1e30f, -1e30f};
#pragma unroll
    for (int r = 0; r < 8; ++r) {
      f32x4 v = *(const f32x4*)(xp + (size_t)r * DIM);
#pragma unroll
      for (int j = 0; j < 4; ++j) {
        mn[j] = fminf(mn[j], v[j]);
        mx[j] = fmaxf(mx[j], v[j]);
      }
    }
    *(f32x4*)(pmin + bid * DIM + (t << 2)) = mn;
    *(f32x4*)(pmax + bid * DIM + (t << 2)) = mx;
  }
  gsync(sync + 0);

  // ---- P2: final reduce + scale (blocks 0..63, 16 cols each) ----
  if (bid < 64) {
    const int cl = t & 15;   // col within block
    const int cs = t >> 4;   // chunk slice 0..15 (32 chunks each)
    const int col = bid * 16 + cl;
    float mn = 1e30f, mx = -1e30f;
#pragma unroll 4
    for (int c = 0; c < 32; ++c) {
      int ch = cs * 32 + c;
      mn = fminf(mn, pmin[ch * DIM + col]);
      mx = fmaxf(mx, pmax[ch * DIM + col]);
    }
    smn[cs][cl] = mn;
    smx[cs][cl] = mx;
    __syncthreads();
    if (t < 16) {
      float m1 = smn[0][t], m2 = smx[0][t];
#pragma unroll
      for (int i = 1; i < 16; ++i) {
        m1 = fminf(m1, smn[i][t]);
        m2 = fmaxf(m2, smx[i][t]);
      }
      minv[bid * 16 + t] = m1;
      scale[bid * 16 + t] = 1.0f / (m2 - m1);
    }
  }
  gsync(sync + 1);

  // ---- P3a: powers (8 rows per block) ----
  {
    const int d = t << 2;
    f32x4 mnv = *(const f32x4*)(minv + d);
    f32x4 scv = *(const f32x4*)(scale + d);
#pragma unroll
    for (int r = 0; r < 8; ++r) {
      const int b = bid * 8 + r;
      f32x4 xv = *(const f32x4*)(x + (size_t)b * DIM + d);
      bf16x4 o3, o2, o1;
#pragma unroll
      for (int j = 0; j < 4; ++j) {
        float xn = (xv[j] - mnv[j]) * scv[j];
        float x2 = xn * xn;
        float x3 = x2 * xn;
        o3[j] = (bf16)x3;
        o2[j] = (bf16)x2;
        o1[j] = (bf16)xn;
      }
      size_t base = (size_t)b * K3 + d;
      *(bf16x4*)(P + base) = o3;
      *(bf16x4*)(P + base + 1024) = o2;
      *(bf16x4*)(P + base + 2048) = o1;
    }
  }
  // ---- P3b: coeff reduce, 2 outputs per block ----
#pragma unroll
  for (int oo = 0; oo < 2; ++oo) {
    const int o = bid * 2 + oo;
    const int d = t << 2;
    f32x4 s[4];
#pragma unroll
    for (int dd = 0; dd < 4; ++dd) {
      const float* p = sp + ((size_t)o * DIM + d + dd) * 16;  // [s=4][4]
      f32x4 acc4 = *(const f32x4*)(p);
      acc4 += *(const f32x4*)(p + 4);
      acc4 += *(const f32x4*)(p + 8);
      acc4 += *(const f32x4*)(p + 12);
      s[dd] = acc4;
    }
    size_t cb = (size_t)o * K3 + d;
    bf16x4 c0 = {(bf16)s[0][0], (bf16)s[1][0], (bf16)s[2][0], (bf16)s[3][0]};
    bf16x4 c1 = {(bf16)s[0][1], (bf16)s[1][1], (bf16)s[2][1], (bf16)s[3][1]};
    bf16x4 c2 = {(bf16)s[0][2], (bf16)s[1][2], (bf16)s[2][2], (bf16)s[3][2]};
    *(bf16x4*)(CB + cb) = c0;
    *(bf16x4*)(CB + cb + 1024) = c1;
    *(bf16x4*)(CB + cb + 2048) = c2;
    float v = s[0][3] + s[1][3] + s[2][3] + s[3][3];
#pragma unroll
    for (int off = 32; off > 0; off >>= 1) v += __shfl_down(v, off, 64);
    if ((t & 63) == 0) red[t >> 6] = v;
    __syncthreads();
    if (t == 0) bias[o] = red[0] + red[1] + red[2] + red[3];
    __syncthreads();  // red reused next oo
  }
  gsync(sync + 2);

  // ---- P4: GEMM, split-K x2. bid = kz*256 + tb; bn-band == bid&7 -> per-XCD
  // B panel (128 cols x 6 KB = 768 KB) stays L2-resident. ----
  const int kz = bid >> 8;
  const int tb = bid & 255;
  const int bm = (tb >> 3) * BM;
  const int bn = (tb & 7) * BN;
  const int wave = t >> 6;
  const int lane = t & 63;
  const int wr = (wave >> 1) * 64;
  const int wc = (wave & 1) * 64;
  const size_t rowbytes = (size_t)K3 * 2;  // 6144
  const size_t kzoff = (size_t)kz * 1536 * 2;

  const char* gAp[4];
  const char* gBp[4];
  int ldso[4];
#pragma unroll
  for (int i = 0; i < 4; ++i) {
    int off = i * 4096 + t * 16;
    int row = off >> 7;
    int q = (off >> 4) & 7;
    int gb = (q ^ (row & 7)) * 16;
    gAp[i] = (const char*)P + (size_t)(bm + row) * rowbytes + kzoff + gb;
    gBp[i] = (const char*)CB + (size_t)(bn + row) * rowbytes + kzoff + gb;
    ldso[i] = i * 4096 + wave * 1024;
  }

  f32x4 acc[4][4] = {};
  const int mrow = lane & 15;
  const int kq = lane >> 4;

  for (int k0 = 0; k0 < NIT; ++k0) {
    const size_t kb = (size_t)k0 * (BKE * 2);
#pragma unroll
    for (int i = 0; i < 4; ++i) ASYNC16(gAp[i] + kb, (char*)sA + ldso[i]);
#pragma unroll
    for (int i = 0; i < 4; ++i) ASYNC16(gBp[i] + kb, (char*)sB + ldso[i]);
    __syncthreads();
#pragma unroll
    for (int ks = 0; ks < 2; ++ks) {
      bf16x8 af[4], bg[4];
#pragma unroll
      for (int i = 0; i < 4; ++i) {
        int row = wr + i * 16 + mrow;
        int sq = (ks * 4 + kq) ^ (row & 7);
        af[i] = *(const bf16x8*)&sA[row * BKE + sq * 8];
      }
#pragma unroll
      for (int j = 0; j < 4; ++j) {
        int row = wc + j * 16 + mrow;
        int sq = (ks * 4 + kq) ^ (row & 7);
        bg[j] = *(const bf16x8*)&sB[row * BKE + sq * 8];
      }
#pragma unroll
      for (int i = 0; i < 4; ++i)
#pragma unroll
        for (int j = 0; j < 4; ++j)
          acc[i][j] = __builtin_amdgcn_mfma_f32_16x16x32_bf16(af[i], bg[j],
                                                              acc[i][j], 0, 0, 0);
    }
    __syncthreads();
  }

  // epilogue: kz=0 stores acc+bias; sync; kz=1 adds its half (plain RMW —
  // partner block is same-XCD by the mod-8 mapping; fences cover the general case)
  const int ccol = lane & 15;
  const int crow = (lane >> 4) * 4;
  if (kz == 0) {
#pragma unroll
    for (int j = 0; j < 4; ++j) {
      const int col = bn + wc + j * 16 + ccol;
      const float bv = bias[col];
#pragma unroll
      for (int i = 0; i < 4; ++i) {
        const int row0 = bm + wr + i * 16 + crow;
#pragma unroll
        for (int r = 0; r < 4; ++r)
          out[(size_t)(row0 + r) * ODIM + col] = acc[i][j][r] + bv;
      }
    }
  }
  gsync(sync + 3);
  if (kz == 1) {
#pragma unroll
    for (int j = 0; j < 4; ++j) {
      const int col = bn + wc + j * 16 + ccol;
#pragma unroll
      for (int i = 0; i < 4; ++i) {
        const int row0 = bm + wr + i * 16 + crow;
#pragma unroll
        for (int r = 0; r < 4; ++r) {
          size_t idx = (size_t)(row0 + r) * ODIM + col;
          out[idx] += acc[i][j][r];
        }
      }
    }
  }
}

extern "C" void kernel_launch(void* const* d_in, const int* in_sizes, int n_in,
                              void* d_out, int out_size, void* d_ws, size_t ws_size,
                              hipStream_t stream) {
  (void)in_sizes; (void)n_in; (void)out_size; (void)ws_size;
  const float* x = (const float*)d_in[0];
  const float* sp = (const float*)d_in[1];
  float* out = (float*)d_out;
  char* ws = (char*)d_ws;

  bf16* Pm = (bf16*)(ws + WS_P);
  bf16* CBm = (bf16*)(ws + WS_CB);
  float* bias = (float*)(ws + WS_BIAS);
  float* pmin = (float*)(ws + WS_PMIN);
  float* pmax = (float*)(ws + WS_PMAX);
  float* minv = (float*)(ws + WS_MINV);
  float* scale = (float*)(ws + WS_SCALE);
  int* sync = (int*)(ws + WS_SYNC);

  hipMemsetAsync(sync, 0, 4 * sizeof(int), stream);
  k_fused<<<NB, 256, 0, stream>>>(x, sp, Pm, CBm, bias, pmin, pmax, minv, scale,
                                  sync, out);
}

// Round 7
// 179.897 us; speedup vs baseline: 2.6522x; 2.6522x over previous
//
#include <hip/hip_runtime.h>
#include <hip/hip_bf16.h>
#include <stdint.h>
#include <stddef.h>

typedef __bf16 bf16;
typedef __attribute__((ext_vector_type(4))) __bf16 bf16x4;
typedef __attribute__((ext_vector_type(8))) __bf16 bf16x8;
typedef __attribute__((ext_vector_type(4))) float f32x4;

#define BATCH 4096
#define DIM 1024
#define ODIM 1024
#define K3 3072

// workspace layout (bytes) — total < 32 MiB (R6 proved >=31.47 MB available)
#define WS_P      0          // bf16 [4096][3072] = 25165824
#define WS_CB     25165824   // bf16 [1024][3072] = 6291456
#define WS_BIAS   31457280   // f32 [1024]
#define WS_PMIN   31461376   // f32 [8][1024] = 32 KB  (outside P: no alias race)
#define WS_PMAX   31494144   // f32 [8][1024] = 32 KB

#define ASYNC16(g, l)                                                          \
  __builtin_amdgcn_global_load_lds(                                            \
      (__attribute__((address_space(1))) void*)(g),                            \
      (__attribute__((address_space(3))) void*)(l), 16, 0, 0)

// ---- kernel 1: column min/max partials. Grid 256 = 8 row-chunks x 32
// col-groups; block reduces 512 rows x 32 cols -> pmin/pmax[8][1024]. ----
__global__ __launch_bounds__(256) void k_part(const float* __restrict__ x,
                                              float* __restrict__ pmin,
                                              float* __restrict__ pmax) {
  __shared__ f32x4 smn[32][8], smx[32][8];
  const int t = threadIdx.x;
  const int ch = blockIdx.x >> 5;   // row chunk 0..7 (512 rows)
  const int cg = blockIdx.x & 31;   // col group 0..31 (32 cols)
  const int lc = (t & 7) * 4;       // col offset within group
  const int rl = t >> 3;            // row lane 0..31

  const float* xp = x + (size_t)(ch * 512 + rl) * DIM + cg * 32 + lc;
  f32x4 mn = {1e30f, 1e30f, 1e30f, 1e30f};
  f32x4 mx = {-1e30f, -1e30f, -1e30f, -1e30f};
#pragma unroll 4
  for (int it = 0; it < 16; ++it) {
    f32x4 v = *(const f32x4*)(xp + (size_t)it * 32 * DIM);
#pragma unroll
    for (int j = 0; j < 4; ++j) {
      mn[j] = fminf(mn[j], v[j]);
      mx[j] = fmaxf(mx[j], v[j]);
    }
  }
  smn[rl][t & 7] = mn;
  smx[rl][t & 7] = mx;
  __syncthreads();
  if (t < 8) {
    f32x4 m1 = smn[0][t], m2 = smx[0][t];
#pragma unroll
    for (int i = 1; i < 32; ++i) {
      f32x4 a = smn[i][t], b = smx[i][t];
#pragma unroll
      for (int j = 0; j < 4; ++j) {
        m1[j] = fminf(m1[j], a[j]);
        m2[j] = fmaxf(m2[j], b[j]);
      }
    }
    *(f32x4*)(pmin + ch * DIM + cg * 32 + t * 4) = m1;
    *(f32x4*)(pmax + ch * DIM + cg * 32 + t * 4) = m2;
  }
}

// ---- kernel 2 (fused prep): blocks 0..511 = powers (8 rows each) + zero out;
//      blocks 512..1023 = coeff reduce (2 outputs each). Each powers block
//      reduces the 64 KB partials in-register (LLC-hot) — no extra dispatch. ----
__global__ __launch_bounds__(256) void k_prep(const float* __restrict__ x,
                                              const float* __restrict__ pmin,
                                              const float* __restrict__ pmax,
                                              bf16* __restrict__ P,
                                              const float* __restrict__ sp,
                                              bf16* __restrict__ CB,
                                              float* __restrict__ bias,
                                              float* __restrict__ out) {
  __shared__ float red[4];
  const int t = threadIdx.x;
  const int bid = blockIdx.x;
  if (bid < 512) {
    const int d = t << 2;
    // final min/max reduce over 8 chunks, in-register
    f32x4 mnv = *(const f32x4*)(pmin + d);
    f32x4 mxv = *(const f32x4*)(pmax + d);
#pragma unroll
    for (int ch = 1; ch < 8; ++ch) {
      f32x4 a = *(const f32x4*)(pmin + ch * DIM + d);
      f32x4 b = *(const f32x4*)(pmax + ch * DIM + d);
#pragma unroll
      for (int j = 0; j < 4; ++j) {
        mnv[j] = fminf(mnv[j], a[j]);
        mxv[j] = fmaxf(mxv[j], b[j]);
      }
    }
    f32x4 scv;
#pragma unroll
    for (int j = 0; j < 4; ++j) scv[j] = 1.0f / (mxv[j] - mnv[j]);
    // powers for 8 rows
#pragma unroll
    for (int r = 0; r < 8; ++r) {
      const int b = bid * 8 + r;
      f32x4 xv = *(const f32x4*)(x + (size_t)b * DIM + d);
      bf16x4 o3, o2, o1;
#pragma unroll
      for (int j = 0; j < 4; ++j) {
        float xn = (xv[j] - mnv[j]) * scv[j];
        float x2 = xn * xn;
        float x3 = x2 * xn;
        o3[j] = (bf16)x3;
        o2[j] = (bf16)x2;
        o1[j] = (bf16)xn;
      }
      size_t base = (size_t)b * K3 + d;
      *(bf16x4*)(P + base) = o3;
      *(bf16x4*)(P + base + 1024) = o2;
      *(bf16x4*)(P + base + 2048) = o1;
    }
    // zero 8 rows of out (gemm epilogue is pure atomicAdd)
    const f32x4 z = {0.f, 0.f, 0.f, 0.f};
    float* op = out + (size_t)bid * 8 * ODIM + d;
#pragma unroll
    for (int r = 0; r < 8; ++r) *(f32x4*)(op + (size_t)r * ODIM) = z;
  } else {
#pragma unroll
    for (int oo = 0; oo < 2; ++oo) {
      const int o = (bid - 512) * 2 + oo;
      const int d = t << 2;
      f32x4 s[4];
#pragma unroll
      for (int dd = 0; dd < 4; ++dd) {
        const float* p = sp + ((size_t)o * DIM + d + dd) * 16;  // [s=4][4]
        f32x4 a = *(const f32x4*)(p);
        a += *(const f32x4*)(p + 4);
        a += *(const f32x4*)(p + 8);
        a += *(const f32x4*)(p + 12);
        s[dd] = a;
      }
      size_t cb = (size_t)o * K3 + d;
      bf16x4 c0 = {(bf16)s[0][0], (bf16)s[1][0], (bf16)s[2][0], (bf16)s[3][0]};
      bf16x4 c1 = {(bf16)s[0][1], (bf16)s[1][1], (bf16)s[2][1], (bf16)s[3][1]};
      bf16x4 c2 = {(bf16)s[0][2], (bf16)s[1][2], (bf16)s[2][2], (bf16)s[3][2]};
      *(bf16x4*)(CB + cb) = c0;
      *(bf16x4*)(CB + cb + 1024) = c1;
      *(bf16x4*)(CB + cb + 2048) = c2;
      float v = s[0][3] + s[1][3] + s[2][3] + s[3][3];
#pragma unroll
      for (int off = 32; off > 0; off >>= 1) v += __shfl_down(v, off, 64);
      if ((t & 63) == 0) red[t >> 6] = v;
      __syncthreads();
      if (t == 0) bias[o] = red[0] + red[1] + red[2] + red[3];
      __syncthreads();
    }
  }
}

// ---- kernel 3: GEMM, split-K x2 -> grid 512 (2 blocks/CU). 128x128 tile,
// BK=64, 4 waves each 64x64 (R5-proven zero-conflict swizzled 16x16x32).
// Epilogue: native f32 atomicAdd into pre-zeroed out; kz=0 folds bias.
// tb&7 -> bn band == XCD id (512%8==0): B panel (768 KB) L2-resident/XCD. ----
#define BM 128
#define BN 128
#define BKE 64
#define KHALF 1536
#define NIT (KHALF / BKE)  // 24
__global__ __launch_bounds__(256, 2) void k_gemm(const bf16* __restrict__ P,
                                                 const bf16* __restrict__ CBm,
                                                 const float* __restrict__ bias,
                                                 float* __restrict__ out) {
  __shared__ bf16 sA[BM * BKE];  // 16 KB
  __shared__ bf16 sB[BN * BKE];  // 16 KB

  const int tid = threadIdx.x;
  const int wave = tid >> 6;
  const int lane = tid & 63;
  const int bid = blockIdx.x;
  const int kz = bid >> 8;        // 0 or 1
  const int tb = bid & 255;
  const int bm = (tb >> 3) * BM;
  const int bn = (tb & 7) * BN;
  const int wr = (wave >> 1) * 64;
  const int wc = (wave & 1) * 64;

  const size_t rowbytes = (size_t)K3 * 2;  // 6144
  const size_t kzoff = (size_t)kz * KHALF * 2;

  const char* gAp[4];
  const char* gBp[4];
  int ldso[4];
#pragma unroll
  for (int i = 0; i < 4; ++i) {
    int off = i * 4096 + tid * 16;
    int row = off >> 7;   // 128B rows
    int q = (off >> 4) & 7;
    int gb = (q ^ (row & 7)) * 16;
    gAp[i] = (const char*)P + (size_t)(bm + row) * rowbytes + kzoff + gb;
    gBp[i] = (const char*)CBm + (size_t)(bn + row) * rowbytes + kzoff + gb;
    ldso[i] = i * 4096 + wave * 1024;
  }

  f32x4 acc[4][4] = {};
  const int mrow = lane & 15;
  const int kq = lane >> 4;

  for (int k0 = 0; k0 < NIT; ++k0) {
    const size_t kb = (size_t)k0 * (BKE * 2);
#pragma unroll
    for (int i = 0; i < 4; ++i) ASYNC16(gAp[i] + kb, (char*)sA + ldso[i]);
#pragma unroll
    for (int i = 0; i < 4; ++i) ASYNC16(gBp[i] + kb, (char*)sB + ldso[i]);
    __syncthreads();
#pragma unroll
    for (int ks = 0; ks < 2; ++ks) {
      bf16x8 af[4], bg[4];
#pragma unroll
      for (int i = 0; i < 4; ++i) {
        int row = wr + i * 16 + mrow;
        int sq = (ks * 4 + kq) ^ (row & 7);
        af[i] = *(const bf16x8*)&sA[row * BKE + sq * 8];
      }
#pragma unroll
      for (int j = 0; j < 4; ++j) {
        int row = wc + j * 16 + mrow;
        int sq = (ks * 4 + kq) ^ (row & 7);
        bg[j] = *(const bf16x8*)&sB[row * BKE + sq * 8];
      }
#pragma unroll
      for (int i = 0; i < 4; ++i)
#pragma unroll
        for (int j = 0; j < 4; ++j)
          acc[i][j] = __builtin_amdgcn_mfma_f32_16x16x32_bf16(af[i], bg[j],
                                                              acc[i][j], 0, 0, 0);
    }
    __syncthreads();
  }

  // epilogue: C/D layout col=lane&15, row=(lane>>4)*4+reg
  const int ccol = lane & 15;
  const int crow = (lane >> 4) * 4;
#pragma unroll
  for (int j = 0; j < 4; ++j) {
    const int col = bn + wc + j * 16 + ccol;
    const float bv = (kz == 0) ? bias[col] : 0.0f;
#pragma unroll
    for (int i = 0; i < 4; ++i) {
      const int row0 = bm + wr + i * 16 + crow;
#pragma unroll
      for (int r = 0; r < 4; ++r)
        unsafeAtomicAdd(&out[(size_t)(row0 + r) * ODIM + col],
                        acc[i][j][r] + bv);
    }
  }
}

extern "C" void kernel_launch(void* const* d_in, const int* in_sizes, int n_in,
                              void* d_out, int out_size, void* d_ws, size_t ws_size,
                              hipStream_t stream) {
  (void)in_sizes; (void)n_in; (void)out_size; (void)ws_size;
  const float* x = (const float*)d_in[0];
  const float* sp = (const float*)d_in[1];
  float* out = (float*)d_out;
  char* ws = (char*)d_ws;

  bf16* Pm = (bf16*)(ws + WS_P);
  bf16* CBm = (bf16*)(ws + WS_CB);
  float* bias = (float*)(ws + WS_BIAS);
  float* pmin = (float*)(ws + WS_PMIN);
  float* pmax = (float*)(ws + WS_PMAX);

  k_part<<<256, 256, 0, stream>>>(x, pmin, pmax);
  k_prep<<<1024, 256, 0, stream>>>(x, pmin, pmax, Pm, sp, CBm, bias, out);
  k_gemm<<<512, 256, 0, stream>>>(Pm, CBm, bias, out);
}